// Round 1
// baseline (3110.833 us; speedup 1.0000x reference)
//
#include <hip/hip_runtime.h>
#include <hip/hip_bf16.h>

// Problem constants (match reference)
#define NB   16     // batch
#define NLQ  256    // queries
#define ND   256    // d_model
#define NDFF 1024
#define NNH  8      // heads
#define NNL  4      // levels
#define NNP  4      // points
#define NDH  32     // head dim
#define NS   21760  // total spatial
#define NLK  272    // 16 sampled + 256 keys

typedef __hip_bfloat16 bf16;

__device__ __constant__ const int c_lvl_w[4]     = {128, 64, 32, 16};
__device__ __constant__ const int c_lvl_start[4] = {0, 16384, 20480, 21504};

// ---------------------------------------------------------------------------
// Generic SGEMM: C[M,N] = A[M,K] @ W[N,K]^T (+bias[N]) (+resid[M,N]) (+relu)
// M % 64 == 0, N % 64 == 0, K % 16 == 0 (all shapes here satisfy this).
// ---------------------------------------------------------------------------
template<typename OT, bool RELU>
__global__ __launch_bounds__(256) void gemm_tn(const float* __restrict__ A,
                                               const float* __restrict__ W,
                                               const float* __restrict__ bias,
                                               const float* __restrict__ resid,
                                               OT* __restrict__ C,
                                               int M, int N, int K) {
  __shared__ float As[16][65];
  __shared__ float Ws[16][65];
  const int tid = threadIdx.x;
  const int tx = tid & 15, ty = tid >> 4;
  const int bn0 = blockIdx.x * 64, bm0 = blockIdx.y * 64;
  const int lr = tid >> 2;          // 0..63 row within tile
  const int lk = (tid & 3) << 2;    // 0,4,8,12
  const float* Ap = A + (size_t)(bm0 + lr) * K + lk;
  const float* Wp = W + (size_t)(bn0 + lr) * K + lk;
  float acc[4][4] = {};
  for (int k0 = 0; k0 < K; k0 += 16) {
    float4 av = *(const float4*)(Ap + k0);
    float4 wv = *(const float4*)(Wp + k0);
    __syncthreads();
    As[lk + 0][lr] = av.x; As[lk + 1][lr] = av.y; As[lk + 2][lr] = av.z; As[lk + 3][lr] = av.w;
    Ws[lk + 0][lr] = wv.x; Ws[lk + 1][lr] = wv.y; Ws[lk + 2][lr] = wv.z; Ws[lk + 3][lr] = wv.w;
    __syncthreads();
#pragma unroll
    for (int k = 0; k < 16; ++k) {
      float a0 = As[k][ty * 4 + 0], a1 = As[k][ty * 4 + 1];
      float a2 = As[k][ty * 4 + 2], a3 = As[k][ty * 4 + 3];
      float b0 = Ws[k][tx * 4 + 0], b1 = Ws[k][tx * 4 + 1];
      float b2 = Ws[k][tx * 4 + 2], b3 = Ws[k][tx * 4 + 3];
      acc[0][0] += a0 * b0; acc[0][1] += a0 * b1; acc[0][2] += a0 * b2; acc[0][3] += a0 * b3;
      acc[1][0] += a1 * b0; acc[1][1] += a1 * b1; acc[1][2] += a1 * b2; acc[1][3] += a1 * b3;
      acc[2][0] += a2 * b0; acc[2][1] += a2 * b1; acc[2][2] += a2 * b2; acc[2][3] += a2 * b3;
      acc[3][0] += a3 * b0; acc[3][1] += a3 * b1; acc[3][2] += a3 * b2; acc[3][3] += a3 * b3;
    }
  }
#pragma unroll
  for (int i = 0; i < 4; ++i) {
    const int row = bm0 + ty * 4 + i;
#pragma unroll
    for (int j = 0; j < 4; ++j) {
      const int col = bn0 + tx * 4 + j;
      float c = acc[i][j];
      if (bias)  c += bias[col];
      if (resid) c += resid[(size_t)row * N + col];
      if (RELU)  c = fmaxf(c, 0.f);
      if constexpr (sizeof(OT) == 2) {
        C[(size_t)row * N + col] = __float2bfloat16(c);
      } else {
        C[(size_t)row * N + col] = c;
      }
    }
  }
}

// concat sp_w|ca_v_w (each 256x256) -> wcat (512x256); biases -> bcat(512)
__global__ __launch_bounds__(256) void concat_w_kernel(const float* __restrict__ w1,
                                                       const float* __restrict__ w2,
                                                       const float* __restrict__ b1,
                                                       const float* __restrict__ b2,
                                                       float* __restrict__ wcat,
                                                       float* __restrict__ bcat) {
  int i = blockIdx.x * 256 + threadIdx.x;  // 0 .. 131071
  if (i < 65536) wcat[i] = w1[i];
  else           wcat[i] = w2[i - 65536];
  if (i < 512)   bcat[i] = (i < 256) ? b1[i] : b2[i - 256];
}

// softmax over the query axis: awl (B, LQ, 128), softmax over LQ per (b, c)
__global__ __launch_bounds__(64) void softmax_q_kernel(float* __restrict__ awl) {
  const int bc = blockIdx.x;         // b*128 + c
  const int c = bc & 127, b = bc >> 7;
  const int lane = threadIdx.x;
  float v[4];
  float mx = -1e30f;
#pragma unroll
  for (int i = 0; i < 4; ++i) {
    int q = lane + 64 * i;
    v[i] = awl[((size_t)(b * NLQ + q)) * 128 + c];
    mx = fmaxf(mx, v[i]);
  }
#pragma unroll
  for (int m = 32; m; m >>= 1) mx = fmaxf(mx, __shfl_xor(mx, m));
  float sum = 0.f;
#pragma unroll
  for (int i = 0; i < 4; ++i) { v[i] = __expf(v[i] - mx); sum += v[i]; }
#pragma unroll
  for (int m = 32; m; m >>= 1) sum += __shfl_xor(sum, m);
  float inv = 1.f / sum;
#pragma unroll
  for (int i = 0; i < 4; ++i) {
    int q = lane + 64 * i;
    awl[((size_t)(b * NLQ + q)) * 128 + c] = v[i] * inv;
  }
}

// softmax over last 16 within each (b,q,h): aw2 (B*LQ, 128) contiguous groups of 16
__global__ __launch_bounds__(128) void softmax16_kernel(float* __restrict__ aw2) {
  const int bq = blockIdx.x;
  const int c = threadIdx.x;
  float v = aw2[(size_t)bq * 128 + c];
  float mx = v;
#pragma unroll
  for (int m = 1; m < 16; m <<= 1) mx = fmaxf(mx, __shfl_xor(mx, m));
  float e = __expf(v - mx);
  float s = e;
#pragma unroll
  for (int m = 1; m < 16; m <<= 1) s += __shfl_xor(s, m);
  aw2[(size_t)bq * 128 + c] = e / s;
}

// Self-attn sampling: sampled[b, lp, h*32+dh] = sum_q aw[b,q,h,lp] * bilin(value)
// vval: (B*S, 512) bf16, cols 0..255 = value (sp_w), 256..511 = val2 (ca_v_w)
__global__ __launch_bounds__(256) void sample_sa_kernel(const bf16* __restrict__ vval,
                                                        const float* __restrict__ off1,
                                                        const float* __restrict__ aw,
                                                        float* __restrict__ sampled) {
  const int bid = blockIdx.x;                // b*128 + h*16 + lp
  const int lp = bid & 15, h = (bid >> 4) & 7, b = bid >> 7;
  const int l = lp >> 2, p = lp & 3;
  const int dh = threadIdx.x & 31, qg = threadIdx.x >> 5;
  const int Wd = c_lvl_w[l], st = c_lvl_start[l];
  const bf16* base = vval + ((size_t)b * NS + st) * 512 + h * 32 + dh;
  float acc = 0.f;
  for (int q = qg; q < NLQ; q += 8) {
    const float* op = off1 + (size_t)(b * NLQ + q) * 256 + ((h * 4 + l) * 4 + p) * 2;
    float x = op[0] - 0.5f;
    float y = op[1] - 0.5f;
    float w = aw[(size_t)(b * NLQ + q) * 128 + h * 16 + lp];
    float x0f = floorf(x), y0f = floorf(y);
    int x0 = (int)x0f, y0 = (int)y0f;
    float wx1 = x - x0f, wy1 = y - y0f;
    float wx0 = 1.f - wx1, wy0 = 1.f - wy1;
    auto tap = [&](int xi, int yi) -> float {
      if (xi < 0 || xi >= Wd || yi < 0 || yi >= Wd) return 0.f;
      return __bfloat162float(base[(size_t)(yi * Wd + xi) * 512]);
    };
    float v00 = tap(x0, y0),     v10 = tap(x0 + 1, y0);
    float v01 = tap(x0, y0 + 1), v11 = tap(x0 + 1, y0 + 1);
    acc += w * (wy0 * (wx0 * v00 + wx1 * v10) + wy1 * (wx0 * v01 + wx1 * v11));
  }
  __shared__ float red[8][32];
  red[qg][dh] = acc;
  __syncthreads();
  if (qg == 0) {
    float s = acc;
#pragma unroll
    for (int g = 1; g < 8; ++g) s += red[g][dh];
    sampled[((size_t)b * 16 + lp) * 256 + h * 32 + dh] = s;
  }
}

// Cross-attn sampling: out2[b,q,h*32+dh] = sum_lp aw2 * bilin(val2)
__global__ __launch_bounds__(256) void sample_ca_kernel(const bf16* __restrict__ vval,
                                                        const float* __restrict__ off2,
                                                        const float* __restrict__ aw2,
                                                        const float* __restrict__ refp,
                                                        float* __restrict__ out2) {
  const int bq = blockIdx.x;                 // b*256 + q
  const int b = bq >> 8, q = bq & 255;
  const int h = threadIdx.x >> 5, dh = threadIdx.x & 31;
  float acc = 0.f;
#pragma unroll
  for (int lp = 0; lp < 16; ++lp) {
    const int l = lp >> 2, p = lp & 3;
    const int Wd = c_lvl_w[l], st = c_lvl_start[l];
    float rx = refp[((size_t)(b * NLQ + q) * 4 + l) * 2 + 0];
    float ry = refp[((size_t)(b * NLQ + q) * 4 + l) * 2 + 1];
    const float* op = off2 + (size_t)(b * NLQ + q) * 256 + ((h * 4 + l) * 4 + p) * 2;
    float x = rx * Wd + op[0] - 0.5f;
    float y = ry * Wd + op[1] - 0.5f;
    float w = aw2[(size_t)(b * NLQ + q) * 128 + h * 16 + lp];
    const bf16* base = vval + ((size_t)b * NS + st) * 512 + 256 + h * 32 + dh;
    float x0f = floorf(x), y0f = floorf(y);
    int x0 = (int)x0f, y0 = (int)y0f;
    float wx1 = x - x0f, wy1 = y - y0f;
    float wx0 = 1.f - wx1, wy0 = 1.f - wy1;
    auto tap = [&](int xi, int yi) -> float {
      if (xi < 0 || xi >= Wd || yi < 0 || yi >= Wd) return 0.f;
      return __bfloat162float(base[(size_t)(yi * Wd + xi) * 512]);
    };
    float v00 = tap(x0, y0),     v10 = tap(x0 + 1, y0);
    float v01 = tap(x0, y0 + 1), v11 = tap(x0 + 1, y0 + 1);
    acc += w * (wy0 * (wx0 * v00 + wx1 * v10) + wy1 * (wx0 * v01 + wx1 * v11));
  }
  out2[(size_t)(b * NLQ + q) * 256 + h * 32 + dh] = acc;
}

// build kcat/vcat: rows 0..15 = sampled, rows 16..271 = k / v
__global__ __launch_bounds__(256) void concat_kv_kernel(const float* __restrict__ sampled,
                                                        const float* __restrict__ kin,
                                                        const float* __restrict__ vin,
                                                        float* __restrict__ kcat,
                                                        float* __restrict__ vcat) {
  const int r = blockIdx.x;                  // 0 .. B*272-1
  const int b = r / NLK, j = r % NLK;
  const int t = threadIdx.x;
  float kv, vv;
  if (j < 16) {
    kv = sampled[((size_t)b * 16 + j) * 256 + t];
    vv = kv;
  } else {
    kv = kin[((size_t)(b * NLQ + (j - 16))) * 256 + t];
    vv = vin[((size_t)(b * NLQ + (j - 16))) * 256 + t];
  }
  kcat[(size_t)r * 256 + t] = kv;
  vcat[(size_t)r * 256 + t] = vv;
}

// one wave per (b,h,q): scores(272) -> softmax -> @ vh -> attno[b,q,h*32+dh]
__global__ __launch_bounds__(64) void attn_kernel(const float* __restrict__ qh,
                                                  const float* __restrict__ kh,
                                                  const float* __restrict__ vh,
                                                  const float* __restrict__ tmask,
                                                  float* __restrict__ attno) {
  const int bid = blockIdx.x;                // b*2048 + h*256 + q
  const int q = bid & 255, h = (bid >> 8) & 7, b = bid >> 11;
  const int lane = threadIdx.x;
  __shared__ float qrow[32];
  __shared__ float p[NLK];
  if (lane < 32) qrow[lane] = qh[((size_t)(b * NLQ + q)) * 256 + h * 32 + lane];
  __syncthreads();
  const float scale = 0.17677669529663687f;  // 1/sqrt(32)
  float s[5];
  float mx = -1e30f;
#pragma unroll
  for (int i = 0; i < 5; ++i) {
    int kk = lane + i * 64;
    float val = -1e30f;
    if (kk < NLK) {
      const float* kr = kh + ((size_t)(b * NLK + kk)) * 256 + h * 32;
      float d = 0.f;
#pragma unroll
      for (int c = 0; c < 32; ++c) d += qrow[c] * kr[c];
      val = d * scale;
      if (kk >= 16) val += tmask[(size_t)q * NLQ + (kk - 16)];
    }
    s[i] = val;
    mx = fmaxf(mx, val);
  }
#pragma unroll
  for (int m = 32; m; m >>= 1) mx = fmaxf(mx, __shfl_xor(mx, m));
  float sum = 0.f;
#pragma unroll
  for (int i = 0; i < 5; ++i) {
    int kk = lane + i * 64;
    if (kk < NLK) { s[i] = __expf(s[i] - mx); sum += s[i]; }
  }
#pragma unroll
  for (int m = 32; m; m >>= 1) sum += __shfl_xor(sum, m);
  const float inv = 1.f / sum;
#pragma unroll
  for (int i = 0; i < 5; ++i) {
    int kk = lane + i * 64;
    if (kk < NLK) p[kk] = s[i] * inv;
  }
  __syncthreads();
  if (lane < 32) {
    float acc = 0.f;
    const float* vb = vh + ((size_t)b * NLK) * 256 + h * 32 + lane;
    for (int kk = 0; kk < NLK; ++kk) acc += p[kk] * vb[(size_t)kk * 256];
    attno[((size_t)(b * NLQ + q)) * 256 + h * 32 + lane] = acc;
  }
}

// out = LayerNorm(resid + x) * g + b ; rows of 256
__global__ __launch_bounds__(256) void add_ln_kernel(const float* __restrict__ resid,
                                                     const float* __restrict__ x,
                                                     const float* __restrict__ g,
                                                     const float* __restrict__ bt,
                                                     float* __restrict__ out) {
  const int row = blockIdx.x;
  const int t = threadIdx.x;
  const size_t idx = (size_t)row * 256 + t;
  float v = resid[idx] + x[idx];
  __shared__ float red[4];
  float s = v;
#pragma unroll
  for (int m = 32; m; m >>= 1) s += __shfl_xor(s, m);
  const int wid = t >> 6;
  if ((t & 63) == 0) red[wid] = s;
  __syncthreads();
  float mean = (red[0] + red[1] + red[2] + red[3]) * (1.f / 256.f);
  float d = v - mean;
  float s2 = d * d;
#pragma unroll
  for (int m = 32; m; m >>= 1) s2 += __shfl_xor(s2, m);
  __syncthreads();
  if ((t & 63) == 0) red[wid] = s2;
  __syncthreads();
  float var = (red[0] + red[1] + red[2] + red[3]) * (1.f / 256.f);
  out[idx] = d * rsqrtf(var + 1e-5f) * g[t] + bt[t];
}

__global__ __launch_bounds__(256) void add_kernel(const float* __restrict__ a,
                                                  const float* __restrict__ b,
                                                  float* __restrict__ c, int n) {
  int i = blockIdx.x * 256 + threadIdx.x;
  if (i < n) c[i] = a[i] + b[i];
}

// ---------------------------------------------------------------------------

static inline void gemm_f32(hipStream_t s, const float* A, const float* W,
                            const float* bias, const float* resid, float* C,
                            int M, int N, int K, bool relu = false) {
  dim3 g(N / 64, M / 64);
  if (relu) gemm_tn<float, true><<<g, 256, 0, s>>>(A, W, bias, resid, C, M, N, K);
  else      gemm_tn<float, false><<<g, 256, 0, s>>>(A, W, bias, resid, C, M, N, K);
}

extern "C" void kernel_launch(void* const* d_in, const int* in_sizes, int n_in,
                              void* d_out, int out_size, void* d_ws, size_t ws_size,
                              hipStream_t stream) {
  const float* tgt      = (const float*)d_in[0];
  const float* qpos     = (const float*)d_in[1];
  const float* refp     = (const float*)d_in[2];
  const float* src      = (const float*)d_in[3];
  const float* tmask    = (const float*)d_in[4];
  const float* wq       = (const float*)d_in[5];
  const float* wk       = (const float*)d_in[6];
  const float* wv       = (const float*)d_in[7];
  const float* so_w     = (const float*)d_in[8];
  const float* so_b     = (const float*)d_in[9];
  const float* sp_w     = (const float*)d_in[10];
  const float* sp_b     = (const float*)d_in[11];
  const float* aw_w     = (const float*)d_in[12];
  const float* aw_b     = (const float*)d_in[13];
  const float* sa_in_w  = (const float*)d_in[14];
  const float* sa_in_b  = (const float*)d_in[15];
  const float* sa_out_w = (const float*)d_in[16];
  const float* sa_out_b = (const float*)d_in[17];
  const float* ca_so_w  = (const float*)d_in[18];
  const float* ca_so_b  = (const float*)d_in[19];
  const float* ca_aw_w  = (const float*)d_in[20];
  const float* ca_aw_b  = (const float*)d_in[21];
  const float* ca_v_w   = (const float*)d_in[22];
  const float* ca_v_b   = (const float*)d_in[23];
  const float* ca_out_w = (const float*)d_in[24];
  const float* ca_out_b = (const float*)d_in[25];
  const float* l1_w     = (const float*)d_in[26];
  const float* l1_b     = (const float*)d_in[27];
  const float* l2_w     = (const float*)d_in[28];
  const float* l2_b     = (const float*)d_in[29];
  const float* n1_g     = (const float*)d_in[30];
  const float* n1_b     = (const float*)d_in[31];
  const float* n2_g     = (const float*)d_in[32];
  const float* n2_b     = (const float*)d_in[33];
  const float* n3_g     = (const float*)d_in[34];
  const float* n3_b     = (const float*)d_in[35];
  float* out = (float*)d_out;

  // ---- workspace layout (floats) ----
  float* f = (float*)d_ws;
  size_t o = 0;
  auto alloc = [&](size_t n) { float* p = f + o; o += n; return p; };
  const size_t R = (size_t)NB * NLQ;        // 4096 rows
  const size_t RK = (size_t)NB * NLK;       // 4352 rows
  float* qb      = alloc(R * 256);
  float* kb      = alloc(R * 256);
  float* vb      = alloc(R * 256);
  float* off1    = alloc(R * 256);
  float* awl     = alloc(R * 128);
  float* sampled = alloc((size_t)NB * 16 * 256);
  float* kcat    = alloc(RK * 256);
  float* vcat    = alloc(RK * 256);
  float* qh      = alloc(R * 256);
  float* kh      = alloc(RK * 256);
  float* vh      = alloc(RK * 256);
  float* attno   = alloc(R * 256);
  float* attnp   = alloc(R * 256);
  float* tgt2    = alloc(R * 256);
  float* qc      = alloc(R * 256);
  float* off2    = alloc(R * 256);
  float* aw2     = alloc(R * 128);
  float* out2    = alloc(R * 256);
  float* out2p   = alloc(R * 256);
  float* tgt3    = alloc(R * 256);
  float* ffn1    = alloc(R * 1024);
  float* ffn2    = alloc(R * 256);
  float* wcat    = alloc(512 * 256);
  float* bcat    = alloc(512);
  bf16* vval = (bf16*)(f + o);              // (B*S, 512) bf16: cols 0..255 value, 256..511 val2

  const int Msrc = NB * NS;                 // 348160

  // ---- 1. fused value projection: vval = src @ [sp_w|ca_v_w]^T + [sp_b|ca_v_b] (bf16) ----
  concat_w_kernel<<<512, 256, 0, stream>>>(sp_w, ca_v_w, sp_b, ca_v_b, wcat, bcat);
  {
    dim3 g(512 / 64, Msrc / 64);
    gemm_tn<bf16, false><<<g, 256, 0, stream>>>(src, wcat, bcat, nullptr, vval, Msrc, 512, 256);
  }

  // ---- 2. projections from tgt ----
  gemm_f32(stream, tgt, wq,  nullptr, qpos, qb, (int)R, 256, 256);   // q = tgt@wq.T + query_pos
  gemm_f32(stream, tgt, wk,  nullptr, nullptr, kb, (int)R, 256, 256);
  gemm_f32(stream, tgt, wv,  nullptr, nullptr, vb, (int)R, 256, 256);
  gemm_f32(stream, tgt, so_w, so_b,  nullptr, off1, (int)R, 256, 256);
  gemm_f32(stream, tgt, aw_w, aw_b,  nullptr, awl, (int)R, 128, 256);

  // ---- 3. aw softmax over query axis, then SA sampling ----
  softmax_q_kernel<<<NB * 128, 64, 0, stream>>>(awl);
  sample_sa_kernel<<<NB * NNH * 16, 256, 0, stream>>>(vval, off1, awl, sampled);

  // ---- 4. self-attention ----
  concat_kv_kernel<<<NB * NLK, 256, 0, stream>>>(sampled, kb, vb, kcat, vcat);
  gemm_f32(stream, qb,   sa_in_w,              sa_in_b,       nullptr, qh, (int)R, 256, 256);
  gemm_f32(stream, kcat, sa_in_w + 256 * 256,  sa_in_b + 256, nullptr, kh, (int)RK, 256, 256);
  gemm_f32(stream, vcat, sa_in_w + 512 * 256,  sa_in_b + 512, nullptr, vh, (int)RK, 256, 256);
  attn_kernel<<<NB * NNH * NLQ, 64, 0, stream>>>(qh, kh, vh, tmask, attno);
  gemm_f32(stream, attno, sa_out_w, sa_out_b, nullptr, attnp, (int)R, 256, 256);
  add_ln_kernel<<<(int)R, 256, 0, stream>>>(tgt, attnp, n2_g, n2_b, tgt2);

  // ---- 5. cross attention (MSDeformAttn) ----
  add_kernel<<<(int)(R * 256 / 256), 256, 0, stream>>>(tgt2, qpos, qc, (int)(R * 256));
  gemm_f32(stream, qc, ca_so_w, ca_so_b, nullptr, off2, (int)R, 256, 256);
  gemm_f32(stream, qc, ca_aw_w, ca_aw_b, nullptr, aw2, (int)R, 128, 256);
  softmax16_kernel<<<(int)R, 128, 0, stream>>>(aw2);
  sample_ca_kernel<<<(int)R, 256, 0, stream>>>(vval, off2, aw2, refp, out2);
  gemm_f32(stream, out2, ca_out_w, ca_out_b, nullptr, out2p, (int)R, 256, 256);
  add_ln_kernel<<<(int)R, 256, 0, stream>>>(tgt2, out2p, n1_g, n1_b, tgt3);

  // ---- 6. FFN ----
  gemm_f32(stream, tgt3, l1_w, l1_b, nullptr, ffn1, (int)R, 1024, 256, true);
  gemm_f32(stream, ffn1, l2_w, l2_b, nullptr, ffn2, (int)R, 256, 1024);
  add_ln_kernel<<<(int)R, 256, 0, stream>>>(tgt3, ffn2, n3_g, n3_b, out);
}

// Round 3
// 1591.180 us; speedup vs baseline: 1.9550x; 1.9550x over previous
//
#include <hip/hip_runtime.h>
#include <hip/hip_bf16.h>

// Problem constants (match reference)
#define NB   16     // batch
#define NLQ  256    // queries
#define ND   256    // d_model
#define NDFF 1024
#define NNH  8      // heads
#define NNL  4      // levels
#define NNP  4      // points
#define NDH  32     // head dim
#define NS   21760  // total spatial
#define NLK  272    // 16 sampled + 256 keys

typedef __hip_bfloat16 bf16;
typedef unsigned short ushort_t;
typedef __bf16 bf16x8 __attribute__((ext_vector_type(8)));
typedef float f32x4 __attribute__((ext_vector_type(4)));
typedef unsigned short us4 __attribute__((ext_vector_type(4)));

__device__ __constant__ const int c_lvl_w[4]     = {128, 64, 32, 16};
__device__ __constant__ const int c_lvl_start[4] = {0, 16384, 20480, 21504};

__device__ __forceinline__ unsigned short f2bf(float x) {
  unsigned int u = __builtin_bit_cast(unsigned int, x);
  u += 0x7FFFu + ((u >> 16) & 1u);
  return (unsigned short)(u >> 16);
}

// ---------------------------------------------------------------------------
// Generic SGEMM: C[M,N] = A[M,K] @ W[N,K]^T (+bias[N]) (+resid[M,N]) (+relu)
// Used for the small (M=4096) projections this round.
// ---------------------------------------------------------------------------
template<typename OT, bool RELU>
__global__ __launch_bounds__(256) void gemm_tn(const float* __restrict__ A,
                                               const float* __restrict__ W,
                                               const float* __restrict__ bias,
                                               const float* __restrict__ resid,
                                               OT* __restrict__ C,
                                               int M, int N, int K) {
  __shared__ float As[16][65];
  __shared__ float Ws[16][65];
  const int tid = threadIdx.x;
  const int tx = tid & 15, ty = tid >> 4;
  const int bn0 = blockIdx.x * 64, bm0 = blockIdx.y * 64;
  const int lr = tid >> 2;          // 0..63 row within tile
  const int lk = (tid & 3) << 2;    // 0,4,8,12
  const float* Ap = A + (size_t)(bm0 + lr) * K + lk;
  const float* Wp = W + (size_t)(bn0 + lr) * K + lk;
  float acc[4][4] = {};
  for (int k0 = 0; k0 < K; k0 += 16) {
    float4 av = *(const float4*)(Ap + k0);
    float4 wv = *(const float4*)(Wp + k0);
    __syncthreads();
    As[lk + 0][lr] = av.x; As[lk + 1][lr] = av.y; As[lk + 2][lr] = av.z; As[lk + 3][lr] = av.w;
    Ws[lk + 0][lr] = wv.x; Ws[lk + 1][lr] = wv.y; Ws[lk + 2][lr] = wv.z; Ws[lk + 3][lr] = wv.w;
    __syncthreads();
#pragma unroll
    for (int k = 0; k < 16; ++k) {
      float a0 = As[k][ty * 4 + 0], a1 = As[k][ty * 4 + 1];
      float a2 = As[k][ty * 4 + 2], a3 = As[k][ty * 4 + 3];
      float b0 = Ws[k][tx * 4 + 0], b1 = Ws[k][tx * 4 + 1];
      float b2 = Ws[k][tx * 4 + 2], b3 = Ws[k][tx * 4 + 3];
      acc[0][0] += a0 * b0; acc[0][1] += a0 * b1; acc[0][2] += a0 * b2; acc[0][3] += a0 * b3;
      acc[1][0] += a1 * b0; acc[1][1] += a1 * b1; acc[1][2] += a1 * b2; acc[1][3] += a1 * b3;
      acc[2][0] += a2 * b0; acc[2][1] += a2 * b1; acc[2][2] += a2 * b2; acc[2][3] += a2 * b3;
      acc[3][0] += a3 * b0; acc[3][1] += a3 * b1; acc[3][2] += a3 * b2; acc[3][3] += a3 * b3;
    }
  }
#pragma unroll
  for (int i = 0; i < 4; ++i) {
    const int row = bm0 + ty * 4 + i;
#pragma unroll
    for (int j = 0; j < 4; ++j) {
      const int col = bn0 + tx * 4 + j;
      float c = acc[i][j];
      if (bias)  c += bias[col];
      if (resid) c += resid[(size_t)row * N + col];
      if (RELU)  c = fmaxf(c, 0.f);
      if constexpr (sizeof(OT) == 2) {
        C[(size_t)row * N + col] = __float2bfloat16(c);
      } else {
        C[(size_t)row * N + col] = c;
      }
    }
  }
}

// ---------------------------------------------------------------------------
// Value-projection MFMA GEMM: vval[M,512](bf16) = src[M,256](f32) @ wcat[512,256](bf16)^T + bcat
// Tile: 128M x 512N (full N, src read ONCE), BK=32, 16 waves (1024 thr),
// wave -> 64x64 out (4x4 frags of 16x16x32 bf16 MFMA).
// LDS rows padded to 40 bf16 (80 B) -> bank stride 20 -> ~2-way (free).
// ---------------------------------------------------------------------------
__global__ __launch_bounds__(1024) void gemm_value_mfma(const float* __restrict__ A,
                                                        const ushort_t* __restrict__ Wb,
                                                        const float* __restrict__ bias,
                                                        ushort_t* __restrict__ C,
                                                        int M) {
  __shared__ __align__(16) ushort_t As[128][40];
  __shared__ __align__(16) ushort_t Bs[512][40];
  const int tid = threadIdx.x;
  const int wid = tid >> 6;        // 0..15
  const int lane = tid & 63;
  const int wm = wid >> 3;         // 0..1  (64-row group)
  const int wn = wid & 7;          // 0..7  (64-col group)
  const int bm0 = blockIdx.x * 128;
  const int lr = lane & 15;        // fragment row/col
  const int lk = (lane >> 4) * 8;  // fragment k-base

  // staging assignments
  const int ar = tid >> 3;               // A row 0..127
  const int ac4 = (tid & 7) * 4;         // A col group (4 floats)
  const int br = tid >> 1;               // B row 0..511
  const int bc16 = (tid & 1) * 16;       // B col group (16 bf16)

  const float* Ap = A + (size_t)(bm0 + ar) * 256 + ac4;
  const ushort_t* Bp = Wb + (size_t)br * 256 + bc16;

  f32x4 acc[4][4] = {};

  for (int k0 = 0; k0 < 256; k0 += 32) {
    float4 av = *(const float4*)(Ap + k0);
    uint4 bv0 = *(const uint4*)(Bp + k0);
    uint4 bv1 = *(const uint4*)(Bp + k0 + 8);
    __syncthreads();               // previous step's compute done
    us4 a4;
    a4[0] = f2bf(av.x); a4[1] = f2bf(av.y); a4[2] = f2bf(av.z); a4[3] = f2bf(av.w);
    *(us4*)&As[ar][ac4] = a4;
    *(uint4*)&Bs[br][bc16] = bv0;
    *(uint4*)&Bs[br][bc16 + 8] = bv1;
    __syncthreads();
    bf16x8 bfr[4];
#pragma unroll
    for (int ni = 0; ni < 4; ++ni)
      bfr[ni] = *(const bf16x8*)&Bs[wn * 64 + ni * 16 + lr][lk];
#pragma unroll
    for (int mi = 0; mi < 4; ++mi) {
      bf16x8 af = *(const bf16x8*)&As[wm * 64 + mi * 16 + lr][lk];
#pragma unroll
      for (int ni = 0; ni < 4; ++ni)
        acc[mi][ni] = __builtin_amdgcn_mfma_f32_16x16x32_bf16(af, bfr[ni], acc[mi][ni], 0, 0, 0);
    }
  }

  float bv[4];
#pragma unroll
  for (int ni = 0; ni < 4; ++ni) bv[ni] = bias[wn * 64 + ni * 16 + lr];
#pragma unroll
  for (int mi = 0; mi < 4; ++mi) {
#pragma unroll
    for (int r = 0; r < 4; ++r) {
      const int row = bm0 + wm * 64 + mi * 16 + (lane >> 4) * 4 + r;
#pragma unroll
      for (int ni = 0; ni < 4; ++ni) {
        const int col = wn * 64 + ni * 16 + lr;
        C[(size_t)row * 512 + col] = f2bf(acc[mi][ni][r] + bv[ni]);
      }
    }
  }
}

// concat sp_w|ca_v_w (each 256x256) -> wcat bf16 (512x256); biases -> bcat(512) f32
__global__ __launch_bounds__(256) void concat_w_kernel(const float* __restrict__ w1,
                                                       const float* __restrict__ w2,
                                                       const float* __restrict__ b1,
                                                       const float* __restrict__ b2,
                                                       ushort_t* __restrict__ wcat,
                                                       float* __restrict__ bcat) {
  int i = blockIdx.x * 256 + threadIdx.x;  // 0 .. 131071
  float v = (i < 65536) ? w1[i] : w2[i - 65536];
  wcat[i] = f2bf(v);
  if (i < 512) bcat[i] = (i < 256) ? b1[i] : b2[i - 256];
}

// softmax over the query axis: awl (B, LQ, 128), softmax over LQ per (b, c)
__global__ __launch_bounds__(64) void softmax_q_kernel(float* __restrict__ awl) {
  const int bc = blockIdx.x;         // b*128 + c
  const int c = bc & 127, b = bc >> 7;
  const int lane = threadIdx.x;
  float v[4];
  float mx = -1e30f;
#pragma unroll
  for (int i = 0; i < 4; ++i) {
    int q = lane + 64 * i;
    v[i] = awl[((size_t)(b * NLQ + q)) * 128 + c];
    mx = fmaxf(mx, v[i]);
  }
#pragma unroll
  for (int m = 32; m; m >>= 1) mx = fmaxf(mx, __shfl_xor(mx, m));
  float sum = 0.f;
#pragma unroll
  for (int i = 0; i < 4; ++i) { v[i] = __expf(v[i] - mx); sum += v[i]; }
#pragma unroll
  for (int m = 32; m; m >>= 1) sum += __shfl_xor(sum, m);
  float inv = 1.f / sum;
#pragma unroll
  for (int i = 0; i < 4; ++i) {
    int q = lane + 64 * i;
    awl[((size_t)(b * NLQ + q)) * 128 + c] = v[i] * inv;
  }
}

// softmax over last 16 within each (b,q,h): aw2 (B*LQ, 128) contiguous groups of 16
__global__ __launch_bounds__(128) void softmax16_kernel(float* __restrict__ aw2) {
  const int bq = blockIdx.x;
  const int c = threadIdx.x;
  float v = aw2[(size_t)bq * 128 + c];
  float mx = v;
#pragma unroll
  for (int m = 1; m < 16; m <<= 1) mx = fmaxf(mx, __shfl_xor(mx, m));
  float e = __expf(v - mx);
  float s = e;
#pragma unroll
  for (int m = 1; m < 16; m <<= 1) s += __shfl_xor(s, m);
  aw2[(size_t)bq * 128 + c] = e / s;
}

// Self-attn sampling: sampled[b, lp, h*32+dh] = sum_q aw[b,q,h,lp] * bilin(value)
// vval: (B*S, 512) bf16, cols 0..255 = value (sp_w), 256..511 = val2 (ca_v_w)
__global__ __launch_bounds__(256) void sample_sa_kernel(const bf16* __restrict__ vval,
                                                        const float* __restrict__ off1,
                                                        const float* __restrict__ aw,
                                                        float* __restrict__ sampled) {
  const int bid = blockIdx.x;                // b*128 + h*16 + lp
  const int lp = bid & 15, h = (bid >> 4) & 7, b = bid >> 7;
  const int l = lp >> 2, p = lp & 3;
  const int dh = threadIdx.x & 31, qg = threadIdx.x >> 5;
  const int Wd = c_lvl_w[l], st = c_lvl_start[l];
  const bf16* base = vval + ((size_t)b * NS + st) * 512 + h * 32 + dh;
  float acc = 0.f;
  for (int q = qg; q < NLQ; q += 8) {
    const float* op = off1 + (size_t)(b * NLQ + q) * 256 + ((h * 4 + l) * 4 + p) * 2;
    float x = op[0] - 0.5f;
    float y = op[1] - 0.5f;
    float w = aw[(size_t)(b * NLQ + q) * 128 + h * 16 + lp];
    float x0f = floorf(x), y0f = floorf(y);
    int x0 = (int)x0f, y0 = (int)y0f;
    float wx1 = x - x0f, wy1 = y - y0f;
    float wx0 = 1.f - wx1, wy0 = 1.f - wy1;
    auto tap = [&](int xi, int yi) -> float {
      if (xi < 0 || xi >= Wd || yi < 0 || yi >= Wd) return 0.f;
      return __bfloat162float(base[(size_t)(yi * Wd + xi) * 512]);
    };
    float v00 = tap(x0, y0),     v10 = tap(x0 + 1, y0);
    float v01 = tap(x0, y0 + 1), v11 = tap(x0 + 1, y0 + 1);
    acc += w * (wy0 * (wx0 * v00 + wx1 * v10) + wy1 * (wx0 * v01 + wx1 * v11));
  }
  __shared__ float red[8][32];
  red[qg][dh] = acc;
  __syncthreads();
  if (qg == 0) {
    float s = acc;
#pragma unroll
    for (int g = 1; g < 8; ++g) s += red[g][dh];
    sampled[((size_t)b * 16 + lp) * 256 + h * 32 + dh] = s;
  }
}

// Cross-attn sampling: out2[b,q,h*32+dh] = sum_lp aw2 * bilin(val2)
__global__ __launch_bounds__(256) void sample_ca_kernel(const bf16* __restrict__ vval,
                                                        const float* __restrict__ off2,
                                                        const float* __restrict__ aw2,
                                                        const float* __restrict__ refp,
                                                        float* __restrict__ out2) {
  const int bq = blockIdx.x;                 // b*256 + q
  const int b = bq >> 8, q = bq & 255;
  const int h = threadIdx.x >> 5, dh = threadIdx.x & 31;
  float acc = 0.f;
#pragma unroll
  for (int lp = 0; lp < 16; ++lp) {
    const int l = lp >> 2, p = lp & 3;
    const int Wd = c_lvl_w[l], st = c_lvl_start[l];
    float rx = refp[((size_t)(b * NLQ + q) * 4 + l) * 2 + 0];
    float ry = refp[((size_t)(b * NLQ + q) * 4 + l) * 2 + 1];
    const float* op = off2 + (size_t)(b * NLQ + q) * 256 + ((h * 4 + l) * 4 + p) * 2;
    float x = rx * Wd + op[0] - 0.5f;
    float y = ry * Wd + op[1] - 0.5f;
    float w = aw2[(size_t)(b * NLQ + q) * 128 + h * 16 + lp];
    const bf16* base = vval + ((size_t)b * NS + st) * 512 + 256 + h * 32 + dh;
    float x0f = floorf(x), y0f = floorf(y);
    int x0 = (int)x0f, y0 = (int)y0f;
    float wx1 = x - x0f, wy1 = y - y0f;
    float wx0 = 1.f - wx1, wy0 = 1.f - wy1;
    auto tap = [&](int xi, int yi) -> float {
      if (xi < 0 || xi >= Wd || yi < 0 || yi >= Wd) return 0.f;
      return __bfloat162float(base[(size_t)(yi * Wd + xi) * 512]);
    };
    float v00 = tap(x0, y0),     v10 = tap(x0 + 1, y0);
    float v01 = tap(x0, y0 + 1), v11 = tap(x0 + 1, y0 + 1);
    acc += w * (wy0 * (wx0 * v00 + wx1 * v10) + wy1 * (wx0 * v01 + wx1 * v11));
  }
  out2[(size_t)(b * NLQ + q) * 256 + h * 32 + dh] = acc;
}

// build kcat/vcat: rows 0..15 = sampled, rows 16..271 = k / v
__global__ __launch_bounds__(256) void concat_kv_kernel(const float* __restrict__ sampled,
                                                        const float* __restrict__ kin,
                                                        const float* __restrict__ vin,
                                                        float* __restrict__ kcat,
                                                        float* __restrict__ vcat) {
  const int r = blockIdx.x;                  // 0 .. B*272-1
  const int b = r / NLK, j = r % NLK;
  const int t = threadIdx.x;
  float kv, vv;
  if (j < 16) {
    kv = sampled[((size_t)b * 16 + j) * 256 + t];
    vv = kv;
  } else {
    kv = kin[((size_t)(b * NLQ + (j - 16))) * 256 + t];
    vv = vin[((size_t)(b * NLQ + (j - 16))) * 256 + t];
  }
  kcat[(size_t)r * 256 + t] = kv;
  vcat[(size_t)r * 256 + t] = vv;
}

// one wave per (b,h,q): scores(272) -> softmax -> @ vh -> attno[b,q,h*32+dh]
__global__ __launch_bounds__(64) void attn_kernel(const float* __restrict__ qh,
                                                  const float* __restrict__ kh,
                                                  const float* __restrict__ vh,
                                                  const float* __restrict__ tmask,
                                                  float* __restrict__ attno) {
  const int bid = blockIdx.x;                // b*2048 + h*256 + q
  const int q = bid & 255, h = (bid >> 8) & 7, b = bid >> 11;
  const int lane = threadIdx.x;
  __shared__ float qrow[32];
  __shared__ float p[NLK];
  if (lane < 32) qrow[lane] = qh[((size_t)(b * NLQ + q)) * 256 + h * 32 + lane];
  __syncthreads();
  const float scale = 0.17677669529663687f;  // 1/sqrt(32)
  float s[5];
  float mx = -1e30f;
#pragma unroll
  for (int i = 0; i < 5; ++i) {
    int kk = lane + i * 64;
    float val = -1e30f;
    if (kk < NLK) {
      const float* kr = kh + ((size_t)(b * NLK + kk)) * 256 + h * 32;
      float d = 0.f;
#pragma unroll
      for (int c = 0; c < 32; ++c) d += qrow[c] * kr[c];
      val = d * scale;
      if (kk >= 16) val += tmask[(size_t)q * NLQ + (kk - 16)];
    }
    s[i] = val;
    mx = fmaxf(mx, val);
  }
#pragma unroll
  for (int m = 32; m; m >>= 1) mx = fmaxf(mx, __shfl_xor(mx, m));
  float sum = 0.f;
#pragma unroll
  for (int i = 0; i < 5; ++i) {
    int kk = lane + i * 64;
    if (kk < NLK) { s[i] = __expf(s[i] - mx); sum += s[i]; }
  }
#pragma unroll
  for (int m = 32; m; m >>= 1) sum += __shfl_xor(sum, m);
  const float inv = 1.f / sum;
#pragma unroll
  for (int i = 0; i < 5; ++i) {
    int kk = lane + i * 64;
    if (kk < NLK) p[kk] = s[i] * inv;
  }
  __syncthreads();
  if (lane < 32) {
    float acc = 0.f;
    const float* vb = vh + ((size_t)b * NLK) * 256 + h * 32 + lane;
    for (int kk = 0; kk < NLK; ++kk) acc += p[kk] * vb[(size_t)kk * 256];
    attno[((size_t)(b * NLQ + q)) * 256 + h * 32 + lane] = acc;
  }
}

// out = LayerNorm(resid + x) * g + b ; rows of 256
__global__ __launch_bounds__(256) void add_ln_kernel(const float* __restrict__ resid,
                                                     const float* __restrict__ x,
                                                     const float* __restrict__ g,
                                                     const float* __restrict__ bt,
                                                     float* __restrict__ out) {
  const int row = blockIdx.x;
  const int t = threadIdx.x;
  const size_t idx = (size_t)row * 256 + t;
  float v = resid[idx] + x[idx];
  __shared__ float red[4];
  float s = v;
#pragma unroll
  for (int m = 32; m; m >>= 1) s += __shfl_xor(s, m);
  const int wid = t >> 6;
  if ((t & 63) == 0) red[wid] = s;
  __syncthreads();
  float mean = (red[0] + red[1] + red[2] + red[3]) * (1.f / 256.f);
  float d = v - mean;
  float s2 = d * d;
#pragma unroll
  for (int m = 32; m; m >>= 1) s2 += __shfl_xor(s2, m);
  __syncthreads();
  if ((t & 63) == 0) red[wid] = s2;
  __syncthreads();
  float var = (red[0] + red[1] + red[2] + red[3]) * (1.f / 256.f);
  out[idx] = d * rsqrtf(var + 1e-5f) * g[t] + bt[t];
}

__global__ __launch_bounds__(256) void add_kernel(const float* __restrict__ a,
                                                  const float* __restrict__ b,
                                                  float* __restrict__ c, int n) {
  int i = blockIdx.x * 256 + threadIdx.x;
  if (i < n) c[i] = a[i] + b[i];
}

// ---------------------------------------------------------------------------

static inline void gemm_f32(hipStream_t s, const float* A, const float* W,
                            const float* bias, const float* resid, float* C,
                            int M, int N, int K, bool relu = false) {
  dim3 g(N / 64, M / 64);
  if (relu) gemm_tn<float, true><<<g, 256, 0, s>>>(A, W, bias, resid, C, M, N, K);
  else      gemm_tn<float, false><<<g, 256, 0, s>>>(A, W, bias, resid, C, M, N, K);
}

extern "C" void kernel_launch(void* const* d_in, const int* in_sizes, int n_in,
                              void* d_out, int out_size, void* d_ws, size_t ws_size,
                              hipStream_t stream) {
  const float* tgt      = (const float*)d_in[0];
  const float* qpos     = (const float*)d_in[1];
  const float* refp     = (const float*)d_in[2];
  const float* src      = (const float*)d_in[3];
  const float* tmask    = (const float*)d_in[4];
  const float* wq       = (const float*)d_in[5];
  const float* wk       = (const float*)d_in[6];
  const float* wv       = (const float*)d_in[7];
  const float* so_w     = (const float*)d_in[8];
  const float* so_b     = (const float*)d_in[9];
  const float* sp_w     = (const float*)d_in[10];
  const float* sp_b     = (const float*)d_in[11];
  const float* aw_w     = (const float*)d_in[12];
  const float* aw_b     = (const float*)d_in[13];
  const float* sa_in_w  = (const float*)d_in[14];
  const float* sa_in_b  = (const float*)d_in[15];
  const float* sa_out_w = (const float*)d_in[16];
  const float* sa_out_b = (const float*)d_in[17];
  const float* ca_so_w  = (const float*)d_in[18];
  const float* ca_so_b  = (const float*)d_in[19];
  const float* ca_aw_w  = (const float*)d_in[20];
  const float* ca_aw_b  = (const float*)d_in[21];
  const float* ca_v_w   = (const float*)d_in[22];
  const float* ca_v_b   = (const float*)d_in[23];
  const float* ca_out_w = (const float*)d_in[24];
  const float* ca_out_b = (const float*)d_in[25];
  const float* l1_w     = (const float*)d_in[26];
  const float* l1_b     = (const float*)d_in[27];
  const float* l2_w     = (const float*)d_in[28];
  const float* l2_b     = (const float*)d_in[29];
  const float* n1_g     = (const float*)d_in[30];
  const float* n1_b     = (const float*)d_in[31];
  const float* n2_g     = (const float*)d_in[32];
  const float* n2_b     = (const float*)d_in[33];
  const float* n3_g     = (const float*)d_in[34];
  const float* n3_b     = (const float*)d_in[35];
  float* out = (float*)d_out;

  // ---- workspace layout (floats) ----
  float* f = (float*)d_ws;
  size_t o = 0;
  auto alloc = [&](size_t n) { float* p = f + o; o += n; return p; };
  const size_t R = (size_t)NB * NLQ;        // 4096 rows
  const size_t RK = (size_t)NB * NLK;       // 4352 rows
  float* qb      = alloc(R * 256);
  float* kb      = alloc(R * 256);
  float* vb      = alloc(R * 256);
  float* off1    = alloc(R * 256);
  float* awl     = alloc(R * 128);
  float* sampled = alloc((size_t)NB * 16 * 256);
  float* kcat    = alloc(RK * 256);
  float* vcat    = alloc(RK * 256);
  float* qh      = alloc(R * 256);
  float* kh      = alloc(RK * 256);
  float* vh      = alloc(RK * 256);
  float* attno   = alloc(R * 256);
  float* attnp   = alloc(R * 256);
  float* tgt2    = alloc(R * 256);
  float* qc      = alloc(R * 256);
  float* off2    = alloc(R * 256);
  float* aw2     = alloc(R * 128);
  float* out2    = alloc(R * 256);
  float* out2p   = alloc(R * 256);
  float* tgt3    = alloc(R * 256);
  float* ffn1    = alloc(R * 1024);
  float* ffn2    = alloc(R * 256);
  ushort_t* wcat = (ushort_t*)alloc(512 * 256 / 2);  // bf16 512x256
  float* bcat    = alloc(512);
  bf16* vval = (bf16*)(f + o);              // (B*S, 512) bf16: cols 0..255 value, 256..511 val2

  const int Msrc = NB * NS;                 // 348160

  // ---- 1. fused value projection (MFMA bf16): vval = src @ [sp_w|ca_v_w]^T + [sp_b|ca_v_b] ----
  concat_w_kernel<<<512, 256, 0, stream>>>(sp_w, ca_v_w, sp_b, ca_v_b, wcat, bcat);
  gemm_value_mfma<<<dim3(Msrc / 128), 1024, 0, stream>>>(src, wcat, bcat, (ushort_t*)vval, Msrc);

  // ---- 2. projections from tgt ----
  gemm_f32(stream, tgt, wq,  nullptr, qpos, qb, (int)R, 256, 256);   // q = tgt@wq.T + query_pos
  gemm_f32(stream, tgt, wk,  nullptr, nullptr, kb, (int)R, 256, 256);
  gemm_f32(stream, tgt, wv,  nullptr, nullptr, vb, (int)R, 256, 256);
  gemm_f32(stream, tgt, so_w, so_b,  nullptr, off1, (int)R, 256, 256);
  gemm_f32(stream, tgt, aw_w, aw_b,  nullptr, awl, (int)R, 128, 256);

  // ---- 3. aw softmax over query axis, then SA sampling ----
  softmax_q_kernel<<<NB * 128, 64, 0, stream>>>(awl);
  sample_sa_kernel<<<NB * NNH * 16, 256, 0, stream>>>(vval, off1, awl, sampled);

  // ---- 4. self-attention ----
  concat_kv_kernel<<<NB * NLK, 256, 0, stream>>>(sampled, kb, vb, kcat, vcat);
  gemm_f32(stream, qb,   sa_in_w,              sa_in_b,       nullptr, qh, (int)R, 256, 256);
  gemm_f32(stream, kcat, sa_in_w + 256 * 256,  sa_in_b + 256, nullptr, kh, (int)RK, 256, 256);
  gemm_f32(stream, vcat, sa_in_w + 512 * 256,  sa_in_b + 512, nullptr, vh, (int)RK, 256, 256);
  attn_kernel<<<NB * NNH * NLQ, 64, 0, stream>>>(qh, kh, vh, tmask, attno);
  gemm_f32(stream, attno, sa_out_w, sa_out_b, nullptr, attnp, (int)R, 256, 256);
  add_ln_kernel<<<(int)R, 256, 0, stream>>>(tgt, attnp, n2_g, n2_b, tgt2);

  // ---- 5. cross attention (MSDeformAttn) ----
  add_kernel<<<(int)(R * 256 / 256), 256, 0, stream>>>(tgt2, qpos, qc, (int)(R * 256));
  gemm_f32(stream, qc, ca_so_w, ca_so_b, nullptr, off2, (int)R, 256, 256);
  gemm_f32(stream, qc, ca_aw_w, ca_aw_b, nullptr, aw2, (int)R, 128, 256);
  softmax16_kernel<<<(int)R, 128, 0, stream>>>(aw2);
  sample_ca_kernel<<<(int)R, 256, 0, stream>>>(vval, off2, aw2, refp, out2);
  gemm_f32(stream, out2, ca_out_w, ca_out_b, nullptr, out2p, (int)R, 256, 256);
  add_ln_kernel<<<(int)R, 256, 0, stream>>>(tgt2, out2p, n1_g, n1_b, tgt3);

  // ---- 6. FFN ----
  gemm_f32(stream, tgt3, l1_w, l1_b, nullptr, ffn1, (int)R, 1024, 256, true);
  gemm_f32(stream, ffn1, l2_w, l2_b, nullptr, ffn2, (int)R, 256, 1024);
  add_ln_kernel<<<(int)R, 256, 0, stream>>>(tgt3, ffn2, n3_g, n3_b, out);
}

// Round 4
// 1290.688 us; speedup vs baseline: 2.4102x; 1.2328x over previous
//
#include <hip/hip_runtime.h>
#include <hip/hip_bf16.h>

// Problem constants (match reference)
#define NB   16     // batch
#define NLQ  256    // queries
#define ND   256    // d_model
#define NDFF 1024
#define NNH  8      // heads
#define NNL  4      // levels
#define NNP  4      // points
#define NDH  32     // head dim
#define NS   21760  // total spatial
#define NLK  272    // 16 sampled + 256 keys

typedef __hip_bfloat16 bf16;
typedef unsigned short ushort_t;
typedef __bf16 bf16x8 __attribute__((ext_vector_type(8)));
typedef float f32x4 __attribute__((ext_vector_type(4)));
typedef unsigned short us4 __attribute__((ext_vector_type(4)));

__device__ __constant__ const int c_lvl_w[4]     = {128, 64, 32, 16};
__device__ __constant__ const int c_lvl_start[4] = {0, 16384, 20480, 21504};

__device__ __forceinline__ unsigned short f2bf(float x) {
  unsigned int u = __builtin_bit_cast(unsigned int, x);
  u += 0x7FFFu + ((u >> 16) & 1u);
  return (unsigned short)(u >> 16);
}

// ---------------------------------------------------------------------------
// bf16 weight region layout (ushort offsets inside wprep)
//   W_V    0        131072  (sp_w | ca_v_w)
//   W_TGT  131072   294912  (wq | wk | wv | so_w | aw_w)
//   W_SA   425984   196608  (sa_in_w)
//   W_SAO  622592    65536  (sa_out_w)
//   W_CA   688128    98304  (ca_so_w | ca_aw_w)
//   W_CAO  786432    65536  (ca_out_w)
//   W_L1   851968   262144  (l1_w)
//   W_L2  1114112   262144  (l2_w)
//   WTOT  1376256
// f32 bias region (bprep): [0..511]=sp_b|ca_v_b, [512..1663]=0x768|so_b|aw_b,
//                          [1664..2047]=ca_so_b|ca_aw_b
// ---------------------------------------------------------------------------
#define WOFF_V    0
#define WOFF_TGT  131072
#define WOFF_SA   425984
#define WOFF_SAO  622592
#define WOFF_CA   688128
#define WOFF_CAO  786432
#define WOFF_L1   851968
#define WOFF_L2   1114112
#define WTOT      1376256

__global__ __launch_bounds__(256) void prep_kernel(
    const float* __restrict__ sp_w, const float* __restrict__ ca_v_w,
    const float* __restrict__ wq, const float* __restrict__ wk,
    const float* __restrict__ wv, const float* __restrict__ so_w,
    const float* __restrict__ aw_w, const float* __restrict__ sa_in_w,
    const float* __restrict__ sa_out_w, const float* __restrict__ ca_so_w,
    const float* __restrict__ ca_aw_w, const float* __restrict__ ca_out_w,
    const float* __restrict__ l1_w, const float* __restrict__ l2_w,
    const float* __restrict__ sp_b, const float* __restrict__ ca_v_b,
    const float* __restrict__ so_b, const float* __restrict__ aw_b,
    const float* __restrict__ ca_so_b, const float* __restrict__ ca_aw_b,
    ushort_t* __restrict__ wout, float* __restrict__ bout) {
  const int stride = gridDim.x * 256;
  for (int i = blockIdx.x * 256 + threadIdx.x; i < WTOT + 2048; i += stride) {
    if (i < WTOT) {
      float v;
      int j = i;
      if (j < 131072) { v = (j < 65536) ? sp_w[j] : ca_v_w[j - 65536]; }
      else if ((j -= 131072) < 294912) {
        if      (j < 65536)  v = wq[j];
        else if (j < 131072) v = wk[j - 65536];
        else if (j < 196608) v = wv[j - 131072];
        else if (j < 262144) v = so_w[j - 196608];
        else                 v = aw_w[j - 262144];
      }
      else if ((j -= 294912) < 196608) v = sa_in_w[j];
      else if ((j -= 196608) < 65536)  v = sa_out_w[j];
      else if ((j -= 65536) < 98304)   v = (j < 65536) ? ca_so_w[j] : ca_aw_w[j - 65536];
      else if ((j -= 98304) < 65536)   v = ca_out_w[j];
      else if ((j -= 65536) < 262144)  v = l1_w[j];
      else { j -= 262144; v = l2_w[j]; }
      wout[i] = f2bf(v);
    } else {
      int j = i - WTOT;
      float v;
      if (j < 512) v = (j < 256) ? sp_b[j] : ca_v_b[j - 256];
      else if (j < 1664) {
        int t = j - 512;
        v = (t < 768) ? 0.f : (t < 1024 ? so_b[t - 768] : aw_b[t - 1024]);
      } else {
        int t = j - 1664;
        v = (t < 256) ? ca_so_b[t] : ca_aw_b[t - 256];
      }
      bout[j] = v;
    }
  }
}

// ---------------------------------------------------------------------------
// Small MFMA GEMM: C[M,N](f32) = (A + A2?)[M,K](f32->bf16) @ Wb[N,K](bf16)^T
//                  + bias + (resid on cols < residN) (+relu)
// Tile 64x64, 4 waves (2x2), each wave 32x32 via 2x2 frags of 16x16x32.
// ---------------------------------------------------------------------------
template<bool RELU>
__global__ __launch_bounds__(256) void gemm_bf16(const float* __restrict__ A,
                                                 const float* __restrict__ A2,
                                                 const ushort_t* __restrict__ Wb,
                                                 const float* __restrict__ bias,
                                                 const float* __restrict__ resid,
                                                 float* __restrict__ C,
                                                 int M, int N, int K,
                                                 int lda, int ldc,
                                                 int residN, int residLd) {
  __shared__ __align__(16) ushort_t As[64][40];
  __shared__ __align__(16) ushort_t Bs[64][40];
  const int tid = threadIdx.x;
  const int wid = tid >> 6;         // 0..3
  const int lane = tid & 63;
  const int wr = wid >> 1, wc = wid & 1;
  const int bn0 = blockIdx.x * 64, bm0 = blockIdx.y * 64;
  const int lr = lane & 15;
  const int lk = (lane >> 4) * 8;

  const int ar = tid >> 2;          // 0..63
  const int ac8 = (tid & 3) * 8;    // 0,8,16,24
  const float* Ap = A + (size_t)(bm0 + ar) * lda + ac8;
  const float* A2p = A2 ? A2 + (size_t)(bm0 + ar) * lda + ac8 : nullptr;
  const ushort_t* Wp = Wb + (size_t)(bn0 + ar) * K + ac8;

  f32x4 acc[2][2] = {};

  for (int k0 = 0; k0 < K; k0 += 32) {
    float4 a0 = *(const float4*)(Ap + k0);
    float4 a1 = *(const float4*)(Ap + k0 + 4);
    uint4 bv = *(const uint4*)(Wp + k0);
    if (A2p) {
      float4 c0 = *(const float4*)(A2p + k0);
      float4 c1 = *(const float4*)(A2p + k0 + 4);
      a0.x += c0.x; a0.y += c0.y; a0.z += c0.z; a0.w += c0.w;
      a1.x += c1.x; a1.y += c1.y; a1.z += c1.z; a1.w += c1.w;
    }
    __syncthreads();
    us4 lo, hi;
    lo[0] = f2bf(a0.x); lo[1] = f2bf(a0.y); lo[2] = f2bf(a0.z); lo[3] = f2bf(a0.w);
    hi[0] = f2bf(a1.x); hi[1] = f2bf(a1.y); hi[2] = f2bf(a1.z); hi[3] = f2bf(a1.w);
    *(us4*)&As[ar][ac8] = lo;
    *(us4*)&As[ar][ac8 + 4] = hi;
    *(uint4*)&Bs[ar][ac8] = bv;
    __syncthreads();
    bf16x8 af[2], bf[2];
#pragma unroll
    for (int mi = 0; mi < 2; ++mi) af[mi] = *(const bf16x8*)&As[wr * 32 + mi * 16 + lr][lk];
#pragma unroll
    for (int ni = 0; ni < 2; ++ni) bf[ni] = *(const bf16x8*)&Bs[wc * 32 + ni * 16 + lr][lk];
#pragma unroll
    for (int mi = 0; mi < 2; ++mi)
#pragma unroll
      for (int ni = 0; ni < 2; ++ni)
        acc[mi][ni] = __builtin_amdgcn_mfma_f32_16x16x32_bf16(af[mi], bf[ni], acc[mi][ni], 0, 0, 0);
  }

#pragma unroll
  for (int mi = 0; mi < 2; ++mi) {
#pragma unroll
    for (int r = 0; r < 4; ++r) {
      const int row = bm0 + wr * 32 + mi * 16 + (lane >> 4) * 4 + r;
#pragma unroll
      for (int ni = 0; ni < 2; ++ni) {
        const int col = bn0 + wc * 32 + ni * 16 + lr;
        float c = acc[mi][ni][r];
        if (bias) c += bias[col];
        if (resid && col < residN) c += resid[(size_t)row * residLd + col];
        if (RELU) c = fmaxf(c, 0.f);
        C[(size_t)row * ldc + col] = c;
      }
    }
  }
}

// ---------------------------------------------------------------------------
// Value-projection MFMA GEMM: vval[M,512](bf16) = src[M,256](f32) @ Wv[512,256](bf16)^T + bias
// Tile: 128M x 512N (full N, src read ONCE), BK=32, 16 waves.
// ---------------------------------------------------------------------------
__global__ __launch_bounds__(1024) void gemm_value_mfma(const float* __restrict__ A,
                                                        const ushort_t* __restrict__ Wb,
                                                        const float* __restrict__ bias,
                                                        ushort_t* __restrict__ C,
                                                        int M) {
  __shared__ __align__(16) ushort_t As[128][40];
  __shared__ __align__(16) ushort_t Bs[512][40];
  const int tid = threadIdx.x;
  const int wid = tid >> 6;        // 0..15
  const int lane = tid & 63;
  const int wm = wid >> 3;         // 0..1
  const int wn = wid & 7;          // 0..7
  const int bm0 = blockIdx.x * 128;
  const int lr = lane & 15;
  const int lk = (lane >> 4) * 8;

  const int ar = tid >> 3;               // A row 0..127
  const int ac4 = (tid & 7) * 4;
  const int br = tid >> 1;               // B row 0..511
  const int bc16 = (tid & 1) * 16;

  const float* Ap = A + (size_t)(bm0 + ar) * 256 + ac4;
  const ushort_t* Bp = Wb + (size_t)br * 256 + bc16;

  f32x4 acc[4][4] = {};

  for (int k0 = 0; k0 < 256; k0 += 32) {
    float4 av = *(const float4*)(Ap + k0);
    uint4 bv0 = *(const uint4*)(Bp + k0);
    uint4 bv1 = *(const uint4*)(Bp + k0 + 8);
    __syncthreads();
    us4 a4;
    a4[0] = f2bf(av.x); a4[1] = f2bf(av.y); a4[2] = f2bf(av.z); a4[3] = f2bf(av.w);
    *(us4*)&As[ar][ac4] = a4;
    *(uint4*)&Bs[br][bc16] = bv0;
    *(uint4*)&Bs[br][bc16 + 8] = bv1;
    __syncthreads();
    bf16x8 bfr[4];
#pragma unroll
    for (int ni = 0; ni < 4; ++ni)
      bfr[ni] = *(const bf16x8*)&Bs[wn * 64 + ni * 16 + lr][lk];
#pragma unroll
    for (int mi = 0; mi < 4; ++mi) {
      bf16x8 af = *(const bf16x8*)&As[wm * 64 + mi * 16 + lr][lk];
#pragma unroll
      for (int ni = 0; ni < 4; ++ni)
        acc[mi][ni] = __builtin_amdgcn_mfma_f32_16x16x32_bf16(af, bfr[ni], acc[mi][ni], 0, 0, 0);
    }
  }

  float bv[4];
#pragma unroll
  for (int ni = 0; ni < 4; ++ni) bv[ni] = bias[wn * 64 + ni * 16 + lr];
#pragma unroll
  for (int mi = 0; mi < 4; ++mi) {
#pragma unroll
    for (int r = 0; r < 4; ++r) {
      const int row = bm0 + wm * 64 + mi * 16 + (lane >> 4) * 4 + r;
#pragma unroll
      for (int ni = 0; ni < 4; ++ni) {
        const int col = wn * 64 + ni * 16 + lr;
        C[(size_t)row * 512 + col] = f2bf(acc[mi][ni][r] + bv[ni]);
      }
    }
  }
}

// softmax over the query axis: awl region of proj1 (B, LQ, ld=1152), cols 0..127
__global__ __launch_bounds__(64) void softmax_q_kernel(float* __restrict__ awl) {
  const int bc = blockIdx.x;         // b*128 + c
  const int c = bc & 127, b = bc >> 7;
  const int lane = threadIdx.x;
  float v[4];
  float mx = -1e30f;
#pragma unroll
  for (int i = 0; i < 4; ++i) {
    int q = lane + 64 * i;
    v[i] = awl[((size_t)(b * NLQ + q)) * 1152 + c];
    mx = fmaxf(mx, v[i]);
  }
#pragma unroll
  for (int m = 32; m; m >>= 1) mx = fmaxf(mx, __shfl_xor(mx, m));
  float sum = 0.f;
#pragma unroll
  for (int i = 0; i < 4; ++i) { v[i] = __expf(v[i] - mx); sum += v[i]; }
#pragma unroll
  for (int m = 32; m; m >>= 1) sum += __shfl_xor(sum, m);
  float inv = 1.f / sum;
#pragma unroll
  for (int i = 0; i < 4; ++i) {
    int q = lane + 64 * i;
    awl[((size_t)(b * NLQ + q)) * 1152 + c] = v[i] * inv;
  }
}

// softmax over 16-point groups: aw2 region of proj2 (B*LQ rows, ld=384), cols 0..127
__global__ __launch_bounds__(128) void softmax16_kernel(float* __restrict__ aw2) {
  const int bq = blockIdx.x;
  const int c = threadIdx.x;
  float v = aw2[(size_t)bq * 384 + c];
  float mx = v;
#pragma unroll
  for (int m = 1; m < 16; m <<= 1) mx = fmaxf(mx, __shfl_xor(mx, m));
  float e = __expf(v - mx);
  float s = e;
#pragma unroll
  for (int m = 1; m < 16; m <<= 1) s += __shfl_xor(s, m);
  aw2[(size_t)bq * 384 + c] = e / s;
}

// Self-attn sampling: sampled[b, lp, h*32+dh] = sum_q aw[b,q,h,lp] * bilin(value)
// off1/aw live in proj1 (ld=1152, col offsets 768 / 896)
__global__ __launch_bounds__(256) void sample_sa_kernel(const bf16* __restrict__ vval,
                                                        const float* __restrict__ off1,
                                                        const float* __restrict__ aw,
                                                        float* __restrict__ sampled) {
  const int bid = blockIdx.x;                // b*128 + h*16 + lp
  const int lp = bid & 15, h = (bid >> 4) & 7, b = bid >> 7;
  const int l = lp >> 2, p = lp & 3;
  const int dh = threadIdx.x & 31, qg = threadIdx.x >> 5;
  const int Wd = c_lvl_w[l], st = c_lvl_start[l];
  const bf16* base = vval + ((size_t)b * NS + st) * 512 + h * 32 + dh;
  float acc = 0.f;
  for (int q = qg; q < NLQ; q += 8) {
    const float* op = off1 + (size_t)(b * NLQ + q) * 1152 + ((h * 4 + l) * 4 + p) * 2;
    float x = op[0] - 0.5f;
    float y = op[1] - 0.5f;
    float w = aw[(size_t)(b * NLQ + q) * 1152 + h * 16 + lp];
    float x0f = floorf(x), y0f = floorf(y);
    int x0 = (int)x0f, y0 = (int)y0f;
    float wx1 = x - x0f, wy1 = y - y0f;
    float wx0 = 1.f - wx1, wy0 = 1.f - wy1;
    auto tap = [&](int xi, int yi) -> float {
      if (xi < 0 || xi >= Wd || yi < 0 || yi >= Wd) return 0.f;
      return __bfloat162float(base[(size_t)(yi * Wd + xi) * 512]);
    };
    float v00 = tap(x0, y0),     v10 = tap(x0 + 1, y0);
    float v01 = tap(x0, y0 + 1), v11 = tap(x0 + 1, y0 + 1);
    acc += w * (wy0 * (wx0 * v00 + wx1 * v10) + wy1 * (wx0 * v01 + wx1 * v11));
  }
  __shared__ float red[8][32];
  red[qg][dh] = acc;
  __syncthreads();
  if (qg == 0) {
    float s = acc;
#pragma unroll
    for (int g = 1; g < 8; ++g) s += red[g][dh];
    sampled[((size_t)b * 16 + lp) * 256 + h * 32 + dh] = s;
  }
}

// Cross-attn sampling: out2[b,q,h*32+dh] = sum_lp aw2 * bilin(val2)
// off2/aw2 live in proj2 (ld=384, col offsets 0 / 256)
__global__ __launch_bounds__(256) void sample_ca_kernel(const bf16* __restrict__ vval,
                                                        const float* __restrict__ off2,
                                                        const float* __restrict__ aw2,
                                                        const float* __restrict__ refp,
                                                        float* __restrict__ out2) {
  const int bq = blockIdx.x;                 // b*256 + q
  const int b = bq >> 8, q = bq & 255;
  const int h = threadIdx.x >> 5, dh = threadIdx.x & 31;
  float acc = 0.f;
#pragma unroll
  for (int lp = 0; lp < 16; ++lp) {
    const int l = lp >> 2, p = lp & 3;
    const int Wd = c_lvl_w[l], st = c_lvl_start[l];
    float rx = refp[((size_t)(b * NLQ + q) * 4 + l) * 2 + 0];
    float ry = refp[((size_t)(b * NLQ + q) * 4 + l) * 2 + 1];
    const float* op = off2 + (size_t)(b * NLQ + q) * 384 + ((h * 4 + l) * 4 + p) * 2;
    float x = rx * Wd + op[0] - 0.5f;
    float y = ry * Wd + op[1] - 0.5f;
    float w = aw2[(size_t)(b * NLQ + q) * 384 + h * 16 + lp];
    const bf16* base = vval + ((size_t)b * NS + st) * 512 + 256 + h * 32 + dh;
    float x0f = floorf(x), y0f = floorf(y);
    int x0 = (int)x0f, y0 = (int)y0f;
    float wx1 = x - x0f, wy1 = y - y0f;
    float wx0 = 1.f - wx1, wy0 = 1.f - wy1;
    auto tap = [&](int xi, int yi) -> float {
      if (xi < 0 || xi >= Wd || yi < 0 || yi >= Wd) return 0.f;
      return __bfloat162float(base[(size_t)(yi * Wd + xi) * 512]);
    };
    float v00 = tap(x0, y0),     v10 = tap(x0 + 1, y0);
    float v01 = tap(x0, y0 + 1), v11 = tap(x0 + 1, y0 + 1);
    acc += w * (wy0 * (wx0 * v00 + wx1 * v10) + wy1 * (wx0 * v01 + wx1 * v11));
  }
  out2[(size_t)(b * NLQ + q) * 256 + h * 32 + dh] = acc;
}

// build kcat/vcat: rows 0..15 = sampled, rows 16..271 = k / v (from proj1, ld=1152)
__global__ __launch_bounds__(256) void concat_kv_kernel(const float* __restrict__ sampled,
                                                        const float* __restrict__ kin,
                                                        const float* __restrict__ vin,
                                                        float* __restrict__ kcat,
                                                        float* __restrict__ vcat) {
  const int r = blockIdx.x;                  // 0 .. B*272-1
  const int b = r / NLK, j = r % NLK;
  const int t = threadIdx.x;
  float kv, vv;
  if (j < 16) {
    kv = sampled[((size_t)b * 16 + j) * 256 + t];
    vv = kv;
  } else {
    kv = kin[((size_t)(b * NLQ + (j - 16))) * 1152 + t];
    vv = vin[((size_t)(b * NLQ + (j - 16))) * 1152 + t];
  }
  kcat[(size_t)r * 256 + t] = kv;
  vcat[(size_t)r * 256 + t] = vv;
}

// one wave per (b,h,q): scores(272) -> softmax -> @ vh -> attno[b,q,h*32+dh]
__global__ __launch_bounds__(64) void attn_kernel(const float* __restrict__ qh,
                                                  const float* __restrict__ kh,
                                                  const float* __restrict__ vh,
                                                  const float* __restrict__ tmask,
                                                  float* __restrict__ attno) {
  const int bid = blockIdx.x;                // b*2048 + h*256 + q
  const int q = bid & 255, h = (bid >> 8) & 7, b = bid >> 11;
  const int lane = threadIdx.x;
  __shared__ float qrow[32];
  __shared__ float p[NLK];
  if (lane < 32) qrow[lane] = qh[((size_t)(b * NLQ + q)) * 256 + h * 32 + lane];
  __syncthreads();
  const float scale = 0.17677669529663687f;  // 1/sqrt(32)
  float s[5];
  float mx = -1e30f;
#pragma unroll
  for (int i = 0; i < 5; ++i) {
    int kk = lane + i * 64;
    float val = -1e30f;
    if (kk < NLK) {
      const float* kr = kh + ((size_t)(b * NLK + kk)) * 256 + h * 32;
      float d = 0.f;
#pragma unroll
      for (int c = 0; c < 32; ++c) d += qrow[c] * kr[c];
      val = d * scale;
      if (kk >= 16) val += tmask[(size_t)q * NLQ + (kk - 16)];
    }
    s[i] = val;
    mx = fmaxf(mx, val);
  }
#pragma unroll
  for (int m = 32; m; m >>= 1) mx = fmaxf(mx, __shfl_xor(mx, m));
  float sum = 0.f;
#pragma unroll
  for (int i = 0; i < 5; ++i) {
    int kk = lane + i * 64;
    if (kk < NLK) { s[i] = __expf(s[i] - mx); sum += s[i]; }
  }
#pragma unroll
  for (int m = 32; m; m >>= 1) sum += __shfl_xor(sum, m);
  const float inv = 1.f / sum;
#pragma unroll
  for (int i = 0; i < 5; ++i) {
    int kk = lane + i * 64;
    if (kk < NLK) p[kk] = s[i] * inv;
  }
  __syncthreads();
  if (lane < 32) {
    float acc = 0.f;
    const float* vb = vh + ((size_t)b * NLK) * 256 + h * 32 + lane;
    for (int kk = 0; kk < NLK; ++kk) acc += p[kk] * vb[(size_t)kk * 256];
    attno[((size_t)(b * NLQ + q)) * 256 + h * 32 + lane] = acc;
  }
}

// out = LayerNorm(resid + x) * g + b ; rows of 256
__global__ __launch_bounds__(256) void add_ln_kernel(const float* __restrict__ resid,
                                                     const float* __restrict__ x,
                                                     const float* __restrict__ g,
                                                     const float* __restrict__ bt,
                                                     float* __restrict__ out) {
  const int row = blockIdx.x;
  const int t = threadIdx.x;
  const size_t idx = (size_t)row * 256 + t;
  float v = resid[idx] + x[idx];
  __shared__ float red[4];
  float s = v;
#pragma unroll
  for (int m = 32; m; m >>= 1) s += __shfl_xor(s, m);
  const int wid = t >> 6;
  if ((t & 63) == 0) red[wid] = s;
  __syncthreads();
  float mean = (red[0] + red[1] + red[2] + red[3]) * (1.f / 256.f);
  float d = v - mean;
  float s2 = d * d;
#pragma unroll
  for (int m = 32; m; m >>= 1) s2 += __shfl_xor(s2, m);
  __syncthreads();
  if ((t & 63) == 0) red[wid] = s2;
  __syncthreads();
  float var = (red[0] + red[1] + red[2] + red[3]) * (1.f / 256.f);
  out[idx] = d * rsqrtf(var + 1e-5f) * g[t] + bt[t];
}

// ---------------------------------------------------------------------------

static inline void gemm_b(hipStream_t s, const float* A, const float* A2,
                          const ushort_t* Wb, const float* bias, const float* resid,
                          float* C, int M, int N, int K, int lda, int ldc,
                          int residN = 0, int residLd = 0, bool relu = false) {
  dim3 g(N / 64, M / 64);
  if (relu) gemm_bf16<true><<<g, 256, 0, s>>>(A, A2, Wb, bias, resid, C, M, N, K, lda, ldc, residN, residLd);
  else      gemm_bf16<false><<<g, 256, 0, s>>>(A, A2, Wb, bias, resid, C, M, N, K, lda, ldc, residN, residLd);
}

extern "C" void kernel_launch(void* const* d_in, const int* in_sizes, int n_in,
                              void* d_out, int out_size, void* d_ws, size_t ws_size,
                              hipStream_t stream) {
  const float* tgt      = (const float*)d_in[0];
  const float* qpos     = (const float*)d_in[1];
  const float* refp     = (const float*)d_in[2];
  const float* src      = (const float*)d_in[3];
  const float* tmask    = (const float*)d_in[4];
  const float* wq       = (const float*)d_in[5];
  const float* wk       = (const float*)d_in[6];
  const float* wv       = (const float*)d_in[7];
  const float* so_w     = (const float*)d_in[8];
  const float* so_b     = (const float*)d_in[9];
  const float* sp_w     = (const float*)d_in[10];
  const float* sp_b     = (const float*)d_in[11];
  const float* aw_w     = (const float*)d_in[12];
  const float* aw_b     = (const float*)d_in[13];
  const float* sa_in_w  = (const float*)d_in[14];
  const float* sa_in_b  = (const float*)d_in[15];
  const float* sa_out_w = (const float*)d_in[16];
  const float* sa_out_b = (const float*)d_in[17];
  const float* ca_so_w  = (const float*)d_in[18];
  const float* ca_so_b  = (const float*)d_in[19];
  const float* ca_aw_w  = (const float*)d_in[20];
  const float* ca_aw_b  = (const float*)d_in[21];
  const float* ca_v_w   = (const float*)d_in[22];
  const float* ca_v_b   = (const float*)d_in[23];
  const float* ca_out_w = (const float*)d_in[24];
  const float* ca_out_b = (const float*)d_in[25];
  const float* l1_w     = (const float*)d_in[26];
  const float* l1_b     = (const float*)d_in[27];
  const float* l2_w     = (const float*)d_in[28];
  const float* l2_b     = (const float*)d_in[29];
  const float* n1_g     = (const float*)d_in[30];
  const float* n1_b     = (const float*)d_in[31];
  const float* n2_g     = (const float*)d_in[32];
  const float* n2_b     = (const float*)d_in[33];
  const float* n3_g     = (const float*)d_in[34];
  const float* n3_b     = (const float*)d_in[35];
  float* out = (float*)d_out;

  // ---- workspace layout (floats) ----
  float* f = (float*)d_ws;
  size_t o = 0;
  auto alloc = [&](size_t n) { float* p = f + o; o += n; return p; };
  const size_t R = (size_t)NB * NLQ;        // 4096 rows
  const size_t RK = (size_t)NB * NLK;       // 4352 rows
  float* proj1   = alloc(R * 1152);   // [q | k | v | off1 | aw]
  float* sampled = alloc((size_t)NB * 16 * 256);
  float* kcat    = alloc(RK * 256);
  float* vcat    = alloc(RK * 256);
  float* qh      = alloc(R * 256);
  float* kh      = alloc(RK * 256);
  float* vh      = alloc(RK * 256);
  float* attno   = alloc(R * 256);
  float* attnp   = alloc(R * 256);
  float* tgt2    = alloc(R * 256);
  float* proj2   = alloc(R * 384);    // [off2 | aw2]
  float* out2    = alloc(R * 256);
  float* out2p   = alloc(R * 256);
  float* tgt3    = alloc(R * 256);
  float* ffn1    = alloc(R * 1024);
  float* ffn2    = alloc(R * 256);
  float* bprep   = alloc(2048);       // f32 biases: bcat_v | b_tgt | b_ca
  ushort_t* wprep = (ushort_t*)alloc(WTOT / 2 + 64);   // all bf16 weights
  bf16* vval = (bf16*)(f + o);        // (B*S, 512) bf16: value | val2

  const float* qb_p   = proj1;          // ld 1152
  const float* kb_p   = proj1 + 256;
  const float* vb_p   = proj1 + 512;
  const float* off1_p = proj1 + 768;
  float*       awl_p  = proj1 + 896;
  float*       off2_p = proj2;          // ld 384
  float*       aw2_p  = proj2 + 256;

  const int Msrc = NB * NS;             // 348160

  // ---- 0. weight prep (fp32 -> bf16, concatenations, fused biases) ----
  prep_kernel<<<2048, 256, 0, stream>>>(sp_w, ca_v_w, wq, wk, wv, so_w, aw_w,
                                        sa_in_w, sa_out_w, ca_so_w, ca_aw_w,
                                        ca_out_w, l1_w, l2_w,
                                        sp_b, ca_v_b, so_b, aw_b, ca_so_b, ca_aw_b,
                                        wprep, bprep);

  // ---- 1. fused value projection (MFMA): vval = src @ [sp_w|ca_v_w]^T + bias ----
  gemm_value_mfma<<<dim3(Msrc / 128), 1024, 0, stream>>>(src, wprep + WOFF_V, bprep,
                                                         (ushort_t*)vval, Msrc);

  // ---- 2. fused tgt projections: proj1 = tgt @ [wq|wk|wv|so_w|aw_w]^T (+qpos on cols<256, +biases) ----
  gemm_b(stream, tgt, nullptr, wprep + WOFF_TGT, bprep + 512, qpos,
         proj1, (int)R, 1152, 256, 256, 1152, 256, 256);

  // ---- 3. aw softmax over query axis, then SA sampling ----
  softmax_q_kernel<<<NB * 128, 64, 0, stream>>>(awl_p);
  sample_sa_kernel<<<NB * NNH * 16, 256, 0, stream>>>(vval, off1_p, awl_p, sampled);

  // ---- 4. self-attention ----
  concat_kv_kernel<<<NB * NLK, 256, 0, stream>>>(sampled, kb_p, vb_p, kcat, vcat);
  gemm_b(stream, qb_p, nullptr, wprep + WOFF_SA,              sa_in_b,       nullptr, qh, (int)R, 256, 256, 1152, 256);
  gemm_b(stream, kcat, nullptr, wprep + WOFF_SA + 256 * 256,  sa_in_b + 256, nullptr, kh, (int)RK, 256, 256, 256, 256);
  gemm_b(stream, vcat, nullptr, wprep + WOFF_SA + 512 * 256,  sa_in_b + 512, nullptr, vh, (int)RK, 256, 256, 256, 256);
  attn_kernel<<<NB * NNH * NLQ, 64, 0, stream>>>(qh, kh, vh, tmask, attno);
  gemm_b(stream, attno, nullptr, wprep + WOFF_SAO, sa_out_b, nullptr, attnp, (int)R, 256, 256, 256, 256);
  add_ln_kernel<<<(int)R, 256, 0, stream>>>(tgt, attnp, n2_g, n2_b, tgt2);

  // ---- 5. cross attention (MSDeformAttn); qc = tgt2 + qpos fused into A-staging ----
  gemm_b(stream, tgt2, qpos, wprep + WOFF_CA, bprep + 1664, nullptr,
         proj2, (int)R, 384, 256, 256, 384);
  softmax16_kernel<<<(int)R, 128, 0, stream>>>(aw2_p);
  sample_ca_kernel<<<(int)R, 256, 0, stream>>>(vval, off2_p, aw2_p, refp, out2);
  gemm_b(stream, out2, nullptr, wprep + WOFF_CAO, ca_out_b, nullptr, out2p, (int)R, 256, 256, 256, 256);
  add_ln_kernel<<<(int)R, 256, 0, stream>>>(tgt2, out2p, n1_g, n1_b, tgt3);

  // ---- 6. FFN ----
  gemm_b(stream, tgt3, nullptr, wprep + WOFF_L1, l1_b, nullptr, ffn1, (int)R, 1024, 256, 256, 1024, 0, 0, true);
  gemm_b(stream, ffn1, nullptr, wprep + WOFF_L2, l2_b, nullptr, ffn2, (int)R, 256, 1024, 1024, 256);
  add_ln_kernel<<<(int)R, 256, 0, stream>>>(tgt3, ffn2, n3_g, n3_b, out);
}